// Round 1
// baseline (1234.433 us; speedup 1.0000x reference)
//
#include <hip/hip_runtime.h>

#define NP    128
#define NR    129
#define KST   132   // K row stride in floats (pad for b128 alignment)
#define NITER 100
#define BLK   320

__device__ __forceinline__ float wmax(float x) {
  #pragma unroll
  for (int s = 1; s < 64; s <<= 1) x = fmaxf(x, __shfl_xor(x, s));
  return x;
}
__device__ __forceinline__ float wsum(float x) {
  #pragma unroll
  for (int s = 1; s < 64; s <<= 1) x += __shfl_xor(x, s);
  return x;
}

// Rescaled log2-domain Sinkhorn:
//   phi = f/(eps*ln2), gamma = g/(eps*ln2), Ct = C/(eps*ln2), K = 2^-Ct
//   phi[n] = La[n] - (Mg + log2( sum_m K[n][m] * 2^(gamma[m]-Mg) ))
//   flow[n][m] = 2^(phi[n] + gamma[m] - Ct[n][m])
__global__ __launch_bounds__(BLK) void emd_sinkhorn(
    const float* __restrict__ j1g, const float* __restrict__ j2g,
    float* __restrict__ out)
{
  __shared__ float K[NR * KST];
  __shared__ float x1[NP], y1[NP], x2[NP], y2[NP];
  __shared__ float La[NR], Lb[NR];
  __shared__ float u[KST], v[KST];
  __shared__ float F[NR], G[NR];
  __shared__ float red[8];

  const int t = threadIdx.x;
  const int l = t & 63;
  const int b = blockIdx.x;
  const float* J1 = j1g + (size_t)b * (NP * 3);
  const float* J2 = j2g + (size_t)b * (NP * 3);
  const float RSC = 72.13475204444817f;  // log2(e)/EPS, EPS=0.02

  // ---- load particles (w temporarily parked in F/G) ----
  if (t < NP) {
    x1[t] = J1[3*t]; y1[t] = J1[3*t+1]; F[t] = J1[3*t+2];
    x2[t] = J2[3*t]; y2[t] = J2[3*t+1]; G[t] = J2[3*t+2];
  }
  __syncthreads();
  const float e1 = wsum(F[l] + F[l + 64]);   // redundant per-wave, identical results
  const float e2 = wsum(G[l] + G[l + 64]);
  const float dE = fabsf(e2 - e1);
  __syncthreads();  // all waves done reading F/G as weights
  if (t < NP) {
    La[t] = __builtin_amdgcn_logf(fmaxf(F[t], 1e-30f));  // log2
    Lb[t] = __builtin_amdgcn_logf(fmaxf(G[t], 1e-30f));
    G[t] = 0.0f;
  }
  if (t == NP) {
    La[NP] = __builtin_amdgcn_logf(fmaxf(fmaxf(e2 - e1, 0.0f), 1e-30f));
    Lb[NP] = __builtin_amdgcn_logf(fmaxf(fmaxf(e1 - e2, 0.0f), 1e-30f));
    G[NP] = 0.0f;
  }
  if (t >= NP && t < NP + 4) { u[t] = 0.0f; v[t] = 0.0f; }  // zero tail pads

  // ---- build K once: rows/cols 0..127 real, row/col 128 = ones, 129..131 = 0 ----
  for (int idx = t; idx < NR * KST; idx += BLK) {
    const int n = idx / KST;
    const int m = idx - n * KST;
    float kv;
    if (m > NP)                kv = 0.0f;
    else if (m == NP || n == NP) kv = 1.0f;
    else {
      const float dx = x2[m] - x1[n] + 1e-12f;
      const float dy = y2[m] - y1[n] + 1e-12f;
      kv = __builtin_amdgcn_exp2f(-__builtin_sqrtf(dx*dx + dy*dy) * RSC);
    }
    K[idx] = kv;
  }

  float Mg, Mf;
  for (int it = 0; it < NITER; ++it) {
    __syncthreads();  // G (and K on first iter) ready
    // ---- PH_A: global max of gamma, u = 2^(gamma - Mg) ----
    Mg = wmax(fmaxf(fmaxf(G[l], G[l + 64]), G[NP]));
    if (t <= NP) u[t] = __builtin_amdgcn_exp2f(G[t] - Mg);
    __syncthreads();
    // ---- PH_B: row matvec s[n] = sum_m K[n][m]*u[m]; F ----
    if (t < 2 * NR) {
      const int row = t >> 1, half = t & 1;
      const float4* Kr = (const float4*)(K + row * KST);
      const float4* U4 = (const float4*)u;
      float s = 0.0f;
      const int q0 = half ? 16 : 0, q1 = half ? 33 : 16;
      for (int q = q0; q < q1; ++q) {
        const float4 kk = Kr[q], uu = U4[q];
        s += kk.x * uu.x; s += kk.y * uu.y; s += kk.z * uu.z; s += kk.w * uu.w;
      }
      s += __shfl_xor(s, 1);
      if (!half) F[row] = La[row] - Mg - __builtin_amdgcn_logf(s);
    }
    __syncthreads();
    // ---- PH_C: Mf, v = 2^(phi - Mf) ----
    Mf = wmax(fmaxf(fmaxf(F[l], F[l + 64]), F[NP]));
    if (t <= NP) v[t] = __builtin_amdgcn_exp2f(F[t] - Mf);
    __syncthreads();
    // ---- PH_D: col matvec s'[m] = sum_n K[n][m]*v[n]; G ----
    if (t < 264) {
      const int cg = t >> 3, rh = t & 7;  // col-group 0..32 (4 cols), row-chunk 0..7
      float s0 = 0.f, s1 = 0.f, s2 = 0.f, s3 = 0.f;
      const int n0 = rh * 17;
      int n1 = n0 + 17; if (n1 > NR) n1 = NR;
      for (int n = n0; n < n1; ++n) {
        const float4 kk = *(const float4*)(K + n * KST + 4 * cg);
        const float vn = v[n];
        s0 += kk.x * vn; s1 += kk.y * vn; s2 += kk.z * vn; s3 += kk.w * vn;
      }
      #pragma unroll
      for (int s = 1; s < 8; s <<= 1) {
        s0 += __shfl_xor(s0, s); s1 += __shfl_xor(s1, s);
        s2 += __shfl_xor(s2, s); s3 += __shfl_xor(s3, s);
      }
      if (rh == 0) {
        const int m = 4 * cg;
        if (m     <= NP) G[m]     = Lb[m]     - Mf - __builtin_amdgcn_logf(s0);
        if (m + 1 <= NP) G[m + 1] = Lb[m + 1] - Mf - __builtin_amdgcn_logf(s1);
        if (m + 2 <= NP) G[m + 2] = Lb[m + 2] - Mf - __builtin_amdgcn_logf(s2);
        if (m + 3 <= NP) G[m + 3] = Lb[m + 3] - Mf - __builtin_amdgcn_logf(s3);
      }
    }
  }
  __syncthreads();

  // ---- emd = sum_{n,m<128} dist * 2^(F[n]+G[m]-dist*RSC) + |dE| ----
  float acc = 0.0f;
  for (int e = t; e < NP * NP; e += BLK) {
    const int n = e >> 7, m = e & (NP - 1);
    const float dx = x2[m] - x1[n] + 1e-12f;
    const float dy = y2[m] - y1[n] + 1e-12f;
    const float d  = __builtin_sqrtf(dx*dx + dy*dy);
    acc += d * __builtin_amdgcn_exp2f(F[n] + G[m] - d * RSC);
  }
  acc = wsum(acc);
  if (l == 0) red[t >> 6] = acc;
  __syncthreads();
  if (t == 0) out[b] = red[0] + red[1] + red[2] + red[3] + red[4] + dE;
}

extern "C" void kernel_launch(void* const* d_in, const int* in_sizes, int n_in,
                              void* d_out, int out_size, void* d_ws, size_t ws_size,
                              hipStream_t stream) {
  const float* j1 = (const float*)d_in[0];
  const float* j2 = (const float*)d_in[1];
  float* outp = (float*)d_out;
  const int batch = in_sizes[0] / (NP * 3);
  hipLaunchKernelGGL(emd_sinkhorn, dim3(batch), dim3(BLK), 0, stream,
                     j1, j2, outp);
}

// Round 2
// 474.217 us; speedup vs baseline: 2.6031x; 2.6031x over previous
//
#include <hip/hip_runtime.h>

#define NP    128
#define NR    129          // real rows/cols (128 + slack bin)
#define PAD   144          // padded to 16*9
#define TK    9            // tile edge per thread
#define NITER 100
#define BLK   256

#define NEGINF (-__builtin_inff())

__device__ __forceinline__ float wmax64(float x) {
  #pragma unroll
  for (int s = 1; s < 64; s <<= 1) x = fmaxf(x, __shfl_xor(x, s));
  return x;
}
__device__ __forceinline__ float wsum64(float x) {
  #pragma unroll
  for (int s = 1; s < 64; s <<= 1) x += __shfl_xor(x, s);
  return x;
}

// Rescaled log2-domain Sinkhorn (exact reordering of the reference):
//   F = f/(eps*ln2), G = g/(eps*ln2), Ct = C*log2(e)/eps, K = 2^-Ct
//   F[n] = La[n] - Mg - log2( sum_m K[n][m] * 2^(G[m]-Mg) )
//   G[m] = Lb[m] - Mf - log2( sum_n K[n][m] * 2^(F[n]-Mf) )
//   flow[n][m] = 2^(F[n] + G[m] - Ct[n][m])
// K (129x129) lives in REGISTERS: thread (i,j) of a 16x16 grid owns the
// 9x9 tile rows 9i..9i+8, cols 9j..9j+8 (padded region = 0).
__global__ __launch_bounds__(BLK, 4) void emd_sinkhorn(
    const float* __restrict__ j1g, const float* __restrict__ j2g,
    float* __restrict__ out)
{
  __shared__ float x1[NP], y1[NP], w1[NP], x2[NP], y2[NP], w2[NP];
  __shared__ float La[NR], Lb[NR];
  __shared__ float F[PAD], G[PAD];
  __shared__ float part[4][PAD];
  __shared__ float mbufG[4], mbufF[4], red[4];

  const int t  = threadIdx.x;
  const int l  = t & 63;
  const int wv = t >> 6;
  const int i  = t >> 4;        // row group 0..15
  const int j  = t & 15;        // col group 0..15
  const int il = i & 3;         // row group within wave
  const int b  = blockIdx.x;
  const int r0 = i * TK, c0 = j * TK;
  const float* J1 = j1g + (size_t)b * (NP * 3);
  const float* J2 = j2g + (size_t)b * (NP * 3);
  const float RSC = 72.13475204444817f;  // log2(e)/EPS, EPS=0.02

  // ---- load particles ----
  if (t < NP) {
    x1[t] = J1[3*t]; y1[t] = J1[3*t+1]; w1[t] = J1[3*t+2];
    x2[t] = J2[3*t]; y2[t] = J2[3*t+1]; w2[t] = J2[3*t+2];
  }
  __syncthreads();

  // ---- energies (each wave computes the same, deterministic) ----
  const float e1 = wsum64(w1[l] + w1[l + 64]);
  const float e2 = wsum64(w2[l] + w2[l + 64]);
  const float dE = fabsf(e2 - e1);

  // ---- init logs / potentials / pads; prime mbufG (G==0 -> max 0) ----
  if (t < NP) {
    La[t] = __builtin_amdgcn_logf(fmaxf(w1[t], 1e-30f));  // log2
    Lb[t] = __builtin_amdgcn_logf(fmaxf(w2[t], 1e-30f));
    G[t] = 0.0f; F[t] = 0.0f;
  }
  if (t == NP) {
    La[NP] = __builtin_amdgcn_logf(fmaxf(fmaxf(e2 - e1, 0.0f), 1e-30f));
    Lb[NP] = __builtin_amdgcn_logf(fmaxf(fmaxf(e1 - e2, 0.0f), 1e-30f));
    G[NP] = 0.0f; F[NP] = 0.0f;
  }
  if (t > NP && t < PAD) { G[t] = NEGINF; F[t] = NEGINF; }
  if (t < 4) mbufG[t] = 0.0f;

  // ---- build register-resident K tile (once) ----
  float Kt[TK][TK];
  float x1r[TK], y1r[TK], x2c[TK], y2c[TK];
  #pragma unroll
  for (int k = 0; k < TK; ++k) {
    const int r = r0 + k, c = c0 + k;
    const int rc = r < NP ? r : NP - 1, cc = c < NP ? c : NP - 1;
    x1r[k] = x1[rc]; y1r[k] = y1[rc];
    x2c[k] = x2[cc]; y2c[k] = y2[cc];
  }
  #pragma unroll
  for (int kr = 0; kr < TK; ++kr) {
    #pragma unroll
    for (int kc = 0; kc < TK; ++kc) {
      const int r = r0 + kr, c = c0 + kc;
      float kv;
      if (r > NP || c > NP)        kv = 0.0f;
      else if (r == NP || c == NP) kv = 1.0f;
      else {
        const float dx = x2c[kc] - x1r[kr] + 1e-12f;
        const float dy = y2c[kc] - y1r[kr] + 1e-12f;
        kv = __builtin_amdgcn_exp2f(-__builtin_sqrtf(dx*dx + dy*dy) * RSC);
      }
      Kt[kr][kc] = kv;
    }
  }
  __syncthreads();

  for (int it = 0; it < NITER; ++it) {
    // ---- row pass: F[n] = La[n] - Mg - log2(sum_m K[n][m] 2^(G[m]-Mg)) ----
    const float Mg = fmaxf(fmaxf(mbufG[0], mbufG[1]), fmaxf(mbufG[2], mbufG[3]));
    float u9[TK];
    #pragma unroll
    for (int kc = 0; kc < TK; ++kc)
      u9[kc] = __builtin_amdgcn_exp2f(G[c0 + kc] - Mg);  // pads: 2^-inf = 0
    float fmaxloc = NEGINF;
    #pragma unroll
    for (int kr = 0; kr < TK; ++kr) {
      float s = ((Kt[kr][0]*u9[0] + Kt[kr][3]*u9[3] + Kt[kr][6]*u9[6])
               + (Kt[kr][1]*u9[1] + Kt[kr][4]*u9[4] + Kt[kr][7]*u9[7]))
               + (Kt[kr][2]*u9[2] + Kt[kr][5]*u9[5] + Kt[kr][8]*u9[8]);
      s += __shfl_xor(s, 1); s += __shfl_xor(s, 2);
      s += __shfl_xor(s, 4); s += __shfl_xor(s, 8);   // sum over j-lanes
      if (j == 0) {
        const int r = r0 + kr;
        if (r <= NP) {
          const float fv = La[r] - Mg - __builtin_amdgcn_logf(s);
          F[r] = fv;
          fmaxloc = fmaxf(fmaxloc, fv);
        }
      }
    }
    const float fm = wmax64(fmaxloc);
    if (l == 0) mbufF[wv] = fm;
    __syncthreads();

    // ---- col pass: G[m] = Lb[m] - Mf - log2(sum_n K[n][m] 2^(F[n]-Mf)) ----
    const float Mf = fmaxf(fmaxf(mbufF[0], mbufF[1]), fmaxf(mbufF[2], mbufF[3]));
    float v9[TK];
    #pragma unroll
    for (int kr = 0; kr < TK; ++kr)
      v9[kr] = __builtin_amdgcn_exp2f(F[r0 + kr] - Mf);
    #pragma unroll
    for (int kc = 0; kc < TK; ++kc) {
      float a = ((Kt[0][kc]*v9[0] + Kt[3][kc]*v9[3] + Kt[6][kc]*v9[6])
               + (Kt[1][kc]*v9[1] + Kt[4][kc]*v9[4] + Kt[7][kc]*v9[7]))
               + (Kt[2][kc]*v9[2] + Kt[5][kc]*v9[5] + Kt[8][kc]*v9[8]);
      a += __shfl_xor(a, 16); a += __shfl_xor(a, 32); // sum over i within wave
      if (il == 0) part[wv][c0 + kc] = a;
    }
    __syncthreads();

    // ---- combine partials, write G, fold in G-max ----
    float gmaxloc = NEGINF;
    if (t < PAD) {
      const float s = part[0][t] + part[1][t] + part[2][t] + part[3][t];
      if (t <= NP) {
        const float gv = Lb[t] - Mf - __builtin_amdgcn_logf(s);
        G[t] = gv;
        gmaxloc = gv;
      }
    }
    const float gm = wmax64(gmaxloc);
    if (l == 0) mbufG[wv] = gm;
    __syncthreads();
  }

  // ---- emd = sum_{n,m<128} dist * 2^(F[n]+G[m]-dist*RSC) + |dE| ----
  float fr[TK], gc[TK];
  #pragma unroll
  for (int k = 0; k < TK; ++k) { fr[k] = F[r0 + k]; gc[k] = G[c0 + k]; }
  float acc = 0.0f;
  #pragma unroll
  for (int kr = 0; kr < TK; ++kr) {
    #pragma unroll
    for (int kc = 0; kc < TK; ++kc) {
      const int r = r0 + kr, c = c0 + kc;
      if (r < NP && c < NP) {
        const float dx = x2c[kc] - x1r[kr] + 1e-12f;
        const float dy = y2c[kc] - y1r[kr] + 1e-12f;
        const float d  = __builtin_sqrtf(dx*dx + dy*dy);
        acc += d * __builtin_amdgcn_exp2f(fr[kr] + gc[kc] - d * RSC);
      }
    }
  }
  acc = wsum64(acc);
  if (l == 0) red[wv] = acc;
  __syncthreads();
  if (t == 0) out[b] = red[0] + red[1] + red[2] + red[3] + dE;
}

extern "C" void kernel_launch(void* const* d_in, const int* in_sizes, int n_in,
                              void* d_out, int out_size, void* d_ws, size_t ws_size,
                              hipStream_t stream) {
  const float* j1 = (const float*)d_in[0];
  const float* j2 = (const float*)d_in[1];
  float* outp = (float*)d_out;
  const int batch = in_sizes[0] / (NP * 3);
  hipLaunchKernelGGL(emd_sinkhorn, dim3(batch), dim3(BLK), 0, stream,
                     j1, j2, outp);
}

// Round 3
// 300.076 us; speedup vs baseline: 4.1137x; 1.5803x over previous
//
#include <hip/hip_runtime.h>

#define NP    128
#define NITER 100
#define BLK   256
#define RSC   72.13475204444817f    // log2(e)/EPS, EPS=0.02
#define IRSC  0.013862943611198906f // EPS*ln2 = 1/RSC

template<int CTRL>
__device__ __forceinline__ float dppf(float x) {
  return __int_as_float(__builtin_amdgcn_update_dpp(
      0, __float_as_int(x), CTRL, 0xf, 0xf, false));
}
// sum all-reduce across a 16-lane DPP row (rotations 1,2,4,8)
__device__ __forceinline__ float rowsum16(float x) {
  x += dppf<0x121>(x);  // row_ror:1
  x += dppf<0x122>(x);  // row_ror:2
  x += dppf<0x124>(x);  // row_ror:4
  x += dppf<0x128>(x);  // row_ror:8
  return x;
}
__device__ __forceinline__ float wsum64(float x) {
  #pragma unroll
  for (int s = 1; s < 64; s <<= 1) x += __shfl_xor(x, s);
  return x;
}

// Linear-domain Sinkhorn (algebraically identical to the log-domain reference):
//   K = 2^(-dist*RSC);  P[n] = a[n]/(K Q)[n];  Q[m] = b[m]/(K^T P)[m]
//   flow[n][m] = P[n]*Q[m]*K[n][m];  all quantities stay within fp32 range
//   (K >= 2^-102 since dist <= sqrt(2), weights >= 1e-30).
// Thread (i,j) of a 16x16 grid holds A = K[8i..][8j..] and B = K[8j..][8i..]
// in registers; both passes reduce over the 16 j-lanes via DPP rotations.
__global__ __launch_bounds__(BLK, 3) void emd_sinkhorn(
    const float* __restrict__ j1g, const float* __restrict__ j2g,
    float* __restrict__ out)
{
  __shared__ __align__(16) float x1s[NP], y1s[NP], x2s[NP], y2s[NP];
  __shared__ __align__(16) float ah[NP + 4], bh[NP + 4];
  __shared__ __align__(16) float Pv[NP + 4], Qv[NP + 4];
  __shared__ float red[4];

  const int t  = threadIdx.x;
  const int l  = t & 63;
  const int wv = t >> 6;
  const int i  = t >> 4;   // row block 0..15
  const int j  = t & 15;   // col block 0..15 (= lane within DPP row)
  const int b  = blockIdx.x;
  const float* J1 = j1g + (size_t)b * (NP * 3);
  const float* J2 = j2g + (size_t)b * (NP * 3);

  // ---- load particles ----
  if (t < NP) {
    x1s[t] = J1[3*t]; y1s[t] = J1[3*t+1]; ah[t] = J1[3*t+2];
    x2s[t] = J2[3*t]; y2s[t] = J2[3*t+1]; bh[t] = J2[3*t+2];
  }
  __syncthreads();

  // ---- exact energies from raw weights (deterministic, redundant/wave) ----
  const float e1 = wsum64(ah[l] + ah[l + 64]);
  const float e2 = wsum64(bh[l] + bh[l + 64]);
  const float dE = fabsf(e2 - e1);
  __syncthreads();  // all reads of raw weights done before flooring in place

  if (t < NP) { ah[t] = fmaxf(ah[t], 1e-30f); bh[t] = fmaxf(bh[t], 1e-30f); }
  if (t == 0) {
    ah[NP] = fmaxf(fmaxf(e2 - e1, 0.0f), 1e-30f);
    bh[NP] = fmaxf(fmaxf(e1 - e2, 0.0f), 1e-30f);
  }
  if (t <= NP) Qv[t] = 1.0f;   // initial scaling vector (g = 0)

  // ---- build register tiles A (rows 8i, cols 8j) and B (rows 8j, cols 8i) ----
  float A[8][8], B[8][8];
  {
    float xcA[8], ycA[8], xcB[8], ycB[8];
    #pragma unroll
    for (int k = 0; k < 8; ++k) {
      xcA[k] = x2s[8*j + k]; ycA[k] = y2s[8*j + k];
      xcB[k] = x2s[8*i + k]; ycB[k] = y2s[8*i + k];
    }
    #pragma unroll
    for (int kr = 0; kr < 8; ++kr) {
      const float xrA = x1s[8*i + kr], yrA = y1s[8*i + kr];
      const float xrB = x1s[8*j + kr], yrB = y1s[8*j + kr];
      #pragma unroll
      for (int kc = 0; kc < 8; ++kc) {
        float dx = xcA[kc] - xrA + 1e-12f, dy = ycA[kc] - yrA + 1e-12f;
        A[kr][kc] = __builtin_amdgcn_exp2f(-__builtin_sqrtf(dx*dx + dy*dy) * RSC);
        dx = xcB[kc] - xrB + 1e-12f; dy = ycB[kc] - yrB + 1e-12f;
        B[kr][kc] = __builtin_amdgcn_exp2f(-__builtin_sqrtf(dx*dx + dy*dy) * RSC);
      }
    }
  }
  __syncthreads();

  const float4 a4a = *(const float4*)&ah[8*i];
  const float4 a4b = *(const float4*)&ah[8*i + 4];
  const float4 b4a = *(const float4*)&bh[8*i];
  const float4 b4b = *(const float4*)&bh[8*i + 4];
  const float aslk = ah[NP], bslk = bh[NP];

  for (int it = 0; it < NITER; ++it) {
    // ---------- row pass: P[n] = a[n] * rcp( sum_m K[n][m] Q[m] ) ----------
    {
      const float4 qa = *(const float4*)&Qv[8*j];
      const float4 qb = *(const float4*)&Qv[8*j + 4];
      const float q128 = Qv[NP];
      float r[8];
      #pragma unroll
      for (int kr = 0; kr < 8; ++kr)
        r[kr] = ((A[kr][0]*qa.x + A[kr][1]*qa.y) + (A[kr][2]*qa.z + A[kr][3]*qa.w))
              + ((A[kr][4]*qb.x + A[kr][5]*qb.y) + (A[kr][6]*qb.z + A[kr][7]*qb.w));
      float rs = ((qa.x + qa.y) + (qa.z + qa.w)) + ((qb.x + qb.y) + (qb.z + qb.w));
      #pragma unroll
      for (int kr = 0; kr < 8; ++kr) r[kr] = rowsum16(r[kr]);
      rs = rowsum16(rs);
      float p[8];
      p[0] = a4a.x * __builtin_amdgcn_rcpf(r[0] + q128);
      p[1] = a4a.y * __builtin_amdgcn_rcpf(r[1] + q128);
      p[2] = a4a.z * __builtin_amdgcn_rcpf(r[2] + q128);
      p[3] = a4a.w * __builtin_amdgcn_rcpf(r[3] + q128);
      p[4] = a4b.x * __builtin_amdgcn_rcpf(r[4] + q128);
      p[5] = a4b.y * __builtin_amdgcn_rcpf(r[5] + q128);
      p[6] = a4b.z * __builtin_amdgcn_rcpf(r[6] + q128);
      p[7] = a4b.w * __builtin_amdgcn_rcpf(r[7] + q128);
      if (j == 0) {
        *(float4*)&Pv[8*i]     = make_float4(p[0], p[1], p[2], p[3]);
        *(float4*)&Pv[8*i + 4] = make_float4(p[4], p[5], p[6], p[7]);
      }
      if (t == 0) Pv[NP] = aslk * __builtin_amdgcn_rcpf(rs + q128);
    }
    __syncthreads();
    // ---------- col pass: Q[m] = b[m] * rcp( sum_n K[n][m] P[n] ) ----------
    {
      const float4 pa = *(const float4*)&Pv[8*j];
      const float4 pb = *(const float4*)&Pv[8*j + 4];
      const float p128 = Pv[NP];
      float c[8];
      #pragma unroll
      for (int kc = 0; kc < 8; ++kc)
        c[kc] = ((B[0][kc]*pa.x + B[1][kc]*pa.y) + (B[2][kc]*pa.z + B[3][kc]*pa.w))
              + ((B[4][kc]*pb.x + B[5][kc]*pb.y) + (B[6][kc]*pb.z + B[7][kc]*pb.w));
      float cs = ((pa.x + pa.y) + (pa.z + pa.w)) + ((pb.x + pb.y) + (pb.z + pb.w));
      #pragma unroll
      for (int kc = 0; kc < 8; ++kc) c[kc] = rowsum16(c[kc]);
      cs = rowsum16(cs);
      float q[8];
      q[0] = b4a.x * __builtin_amdgcn_rcpf(c[0] + p128);
      q[1] = b4a.y * __builtin_amdgcn_rcpf(c[1] + p128);
      q[2] = b4a.z * __builtin_amdgcn_rcpf(c[2] + p128);
      q[3] = b4a.w * __builtin_amdgcn_rcpf(c[3] + p128);
      q[4] = b4b.x * __builtin_amdgcn_rcpf(c[4] + p128);
      q[5] = b4b.y * __builtin_amdgcn_rcpf(c[5] + p128);
      q[6] = b4b.z * __builtin_amdgcn_rcpf(c[6] + p128);
      q[7] = b4b.w * __builtin_amdgcn_rcpf(c[7] + p128);
      if (j == 0) {
        *(float4*)&Qv[8*i]     = make_float4(q[0], q[1], q[2], q[3]);
        *(float4*)&Qv[8*i + 4] = make_float4(q[4], q[5], q[6], q[7]);
      }
      if (t == 0) Qv[NP] = bslk * __builtin_amdgcn_rcpf(cs + p128);
    }
    __syncthreads();
  }

  // ---- emd = sum_{n,m<128} d * P[n]*Q[m]*K[n][m] + dE ;  d = -log2(K)/RSC ----
  float pr[8], qc[8];
  {
    const float4 pa = *(const float4*)&Pv[8*i];
    const float4 pb = *(const float4*)&Pv[8*i + 4];
    const float4 qa = *(const float4*)&Qv[8*j];
    const float4 qb = *(const float4*)&Qv[8*j + 4];
    pr[0]=pa.x; pr[1]=pa.y; pr[2]=pa.z; pr[3]=pa.w;
    pr[4]=pb.x; pr[5]=pb.y; pr[6]=pb.z; pr[7]=pb.w;
    qc[0]=qa.x; qc[1]=qa.y; qc[2]=qa.z; qc[3]=qa.w;
    qc[4]=qb.x; qc[5]=qb.y; qc[6]=qb.z; qc[7]=qb.w;
  }
  float acc = 0.0f;
  #pragma unroll
  for (int kr = 0; kr < 8; ++kr) {
    #pragma unroll
    for (int kc = 0; kc < 8; ++kc) {
      const float k = A[kr][kc];
      const float d = -__builtin_amdgcn_logf(k) * IRSC;
      acc = fmaf(d, (pr[kr] * k) * qc[kc], acc);
    }
  }
  acc = wsum64(acc);
  if (l == 0) red[wv] = acc;
  __syncthreads();
  if (t == 0) out[b] = ((red[0] + red[1]) + (red[2] + red[3])) + dE;
}

extern "C" void kernel_launch(void* const* d_in, const int* in_sizes, int n_in,
                              void* d_out, int out_size, void* d_ws, size_t ws_size,
                              hipStream_t stream) {
  const float* j1 = (const float*)d_in[0];
  const float* j2 = (const float*)d_in[1];
  float* outp = (float*)d_out;
  const int batch = in_sizes[0] / (NP * 3);
  hipLaunchKernelGGL(emd_sinkhorn, dim3(batch), dim3(BLK), 0, stream,
                     j1, j2, outp);
}